// Round 10
// baseline (452.039 us; speedup 1.0000x reference)
//
#include <hip/hip_runtime.h>
#include <hip/hip_bf16.h>
#include <math.h>

#define EMBED   256
#define KDIM    512
#define BATCH   256
#define BM      128
#define VOCAB   50000

typedef float  f32x4   __attribute__((ext_vector_type(4)));
typedef __bf16 bf16x8  __attribute__((ext_vector_type(8)));
typedef unsigned short ushort8 __attribute__((ext_vector_type(8)));

__device__ __forceinline__ unsigned short f2h(float f) {
    unsigned int u = __float_as_uint(f);
    u += 0x7FFFu + ((u >> 16) & 1u);
    return (unsigned short)(u >> 16);
}
__device__ __forceinline__ float h2f(unsigned short h) {
    return __uint_as_float(((unsigned int)h) << 16);
}
// async global->LDS, 16B/lane; LDS dest = wave-uniform base + lane*16; global src per-lane
__device__ __forceinline__ void gload16(const void* g, void* l) {
    __builtin_amdgcn_global_load_lds(
        (const __attribute__((address_space(1))) unsigned int*)g,
        (__attribute__((address_space(3))) unsigned int*)l, 16, 0, 0);
}

// ---------------- prep: split(relu(emb)) -> bf16 hi/lo tables ----------------
__global__ __launch_bounds__(256) void prep_emb(const float* __restrict__ emb,
                                                unsigned short* __restrict__ Eh,
                                                unsigned short* __restrict__ El)
{
    const size_t base = ((size_t)blockIdx.x * 256 + threadIdx.x) * 8;   // 12.8M elems
    float v[8];
    *(float4*)&v[0] = *(const float4*)&emb[base];
    *(float4*)&v[4] = *(const float4*)&emb[base + 4];
    ushort8 hs, ls;
    #pragma unroll
    for (int i = 0; i < 8; ++i) {
        const float f = fmaxf(v[i], 0.f);
        const unsigned short h = f2h(f);
        hs[i] = h;
        ls[i] = f2h(f - h2f(h));
    }
    *(ushort8*)&Eh[base] = hs;
    *(ushort8*)&El[base] = ls;
}

__global__ __launch_bounds__(256) void prep_w(const float* __restrict__ W,
                                              unsigned short* __restrict__ Wh,
                                              unsigned short* __restrict__ Wl)
{
    const int i = blockIdx.x * 256 + threadIdx.x;   // 131072 elems
    const float w = W[i];
    const unsigned short h = f2h(w);
    Wh[i] = h;
    Wl[i] = f2h(w - h2f(h));
}

// ---------------- main tree GEMM (levels 1..4) — round-4 structure ----------------
// 512 thr / 8 waves, block 128x256, wave 64x64, acc[4][4], BK=32, single-buffer,
// 2-barrier K-loop (~2 blocks/CU). Split-bf16 hi/lo, 3 MFMA passes.
// LV1: A rows from pre-split emb tables Eh/El, token-indexed per-lane gload16.
template<int LV1, int WPREP>
__global__ __launch_bounds__(512) void gemm_tree(
    const unsigned short* __restrict__ Xh, const unsigned short* __restrict__ Xl,
    const unsigned short* __restrict__ Wh, const unsigned short* __restrict__ Wl,
    const float*  __restrict__ Wf,
    const float*  __restrict__ bias,
    unsigned short* __restrict__ Yh, unsigned short* __restrict__ Yl,
    const int* __restrict__ tok,
    const unsigned short* __restrict__ Eh, const unsigned short* __restrict__ El)
{
    // fragment-order LDS: subtile s = 16 rows x 32 k = 512 ushort at s*512, lane slot l*8
    __shared__ __align__(16) unsigned short AhL[4096], AlL[4096];    // 128 x 32 hi/lo
    __shared__ __align__(16) unsigned short BhL[8192], BlL[8192];    // 256 x 32 hi/lo

    const int tid = threadIdx.x;
    const int wid = tid >> 6;          // 0..7
    const int l   = tid & 63;
    const int q   = l >> 4;
    const int rr  = l & 15;
    const int m0  = blockIdx.x * BM;

    const int waveM = wid >> 2;        // 0..1 -> rows waveM*64..
    const int waveN = wid & 3;         // 0..3 -> cols waveN*64..

    int tk0 = 0, tk1 = 0;
    if constexpr (LV1) {
        const int r = m0 + wid * 16 + rr;
        tk0 = tok[2 * r];
        tk1 = tok[2 * r + 1];
    }

    f32x4 acc[4][4] = {};

    for (int t = 0; t < 16; ++t) {
        const int k0   = t << 5;
        const int joff = k0 >> 8;
        const int c    = (k0 & 255) + q * 8;

        // ---- stage A (wave wid owns subtile wid) ----
        if constexpr (LV1) {
            const size_t off = (size_t)(joff ? tk1 : tk0) * EMBED + c;   // per-lane src
            gload16(Eh + off, &AhL[wid * 512]);
            gload16(El + off, &AlL[wid * 512]);
        } else {
            const size_t off = (size_t)(2 * (m0 + wid * 16 + rr) + joff) * EMBED + c;
            gload16(Xh + off, &AhL[wid * 512]);
            gload16(Xl + off, &AlL[wid * 512]);
        }

        // ---- stage B (wave wid owns subtiles wid, wid+8) ----
        #pragma unroll
        for (int g = 0; g < 2; ++g) {
            const int s = wid + g * 8;
            if constexpr (WPREP) {
                const size_t off = (size_t)(s * 16 + rr) * KDIM + k0 + q * 8;
                gload16(Wh + off, &BhL[s * 512]);
                gload16(Wl + off, &BlL[s * 512]);
            } else {
                const float* ws = Wf + (size_t)(s * 16 + rr) * KDIM + k0 + q * 8;
                float v[8];
                *(float4*)&v[0] = *(const float4*)ws;
                *(float4*)&v[4] = *(const float4*)(ws + 4);
                ushort8 hs, ls;
                #pragma unroll
                for (int i = 0; i < 8; ++i) {
                    const unsigned short h = f2h(v[i]);
                    hs[i] = h;
                    ls[i] = f2h(v[i] - h2f(h));
                }
                *(ushort8*)&BhL[s * 512 + l * 8] = hs;
                *(ushort8*)&BlL[s * 512 + l * 8] = ls;
            }
        }

        __syncthreads();   // staged tile visible

        bf16x8 ah[4], al[4], bh[4], bl[4];
        #pragma unroll
        for (int mi = 0; mi < 4; ++mi) {
            ah[mi] = *(const bf16x8*)&AhL[(waveM * 4 + mi) * 512 + l * 8];
            al[mi] = *(const bf16x8*)&AlL[(waveM * 4 + mi) * 512 + l * 8];
        }
        #pragma unroll
        for (int ni = 0; ni < 4; ++ni) {
            bh[ni] = *(const bf16x8*)&BhL[(waveN * 4 + ni) * 512 + l * 8];
            bl[ni] = *(const bf16x8*)&BlL[(waveN * 4 + ni) * 512 + l * 8];
        }
        #pragma unroll
        for (int mi = 0; mi < 4; ++mi)
            #pragma unroll
            for (int ni = 0; ni < 4; ++ni)
                acc[mi][ni] = __builtin_amdgcn_mfma_f32_16x16x32_bf16(ah[mi], bh[ni], acc[mi][ni], 0, 0, 0);
        #pragma unroll
        for (int mi = 0; mi < 4; ++mi)
            #pragma unroll
            for (int ni = 0; ni < 4; ++ni)
                acc[mi][ni] = __builtin_amdgcn_mfma_f32_16x16x32_bf16(al[mi], bh[ni], acc[mi][ni], 0, 0, 0);
        #pragma unroll
        for (int mi = 0; mi < 4; ++mi)
            #pragma unroll
            for (int ni = 0; ni < 4; ++ni)
                acc[mi][ni] = __builtin_amdgcn_mfma_f32_16x16x32_bf16(ah[mi], bl[ni], acc[mi][ni], 0, 0, 0);

        __syncthreads();   // reads done before next-step overwrite
    }

    // ---- epilogue: bias + relu + hi/lo split store (C/D: col=l&15, row=(l>>4)*4+jj) ----
    #pragma unroll
    for (int ni = 0; ni < 4; ++ni) {
        const int col = waveN * 64 + ni * 16 + rr;
        const float bv = bias[col];
        #pragma unroll
        for (int mi = 0; mi < 4; ++mi) {
            const int row0 = m0 + waveM * 64 + mi * 16 + q * 4;
            #pragma unroll
            for (int jj = 0; jj < 4; ++jj) {
                const float y = fmaxf(acc[mi][ni][jj] + bv, 0.f);
                const unsigned short h = f2h(y);
                Yh[(size_t)(row0 + jj) * EMBED + col] = h;
                Yl[(size_t)(row0 + jj) * EMBED + col] = f2h(y - h2f(h));
            }
        }
    }
}

// ---------------- fused tail: levels 5..10 + head, one block per batch element ----------------
// s=0 (L5): A streamed from global (L4 out) via dbuf LDS; Mout=32 (acc[2][4]).
// s>=1: A from X ping-pong LDS (XOR-swizzled); Mout=16,8,4,2,1 (acc[0] only).
template<int WPREP>
__global__ __launch_bounds__(256) void tail_kernel(
    const unsigned short* __restrict__ A4h, const unsigned short* __restrict__ A4l,  // L4 out: 16384 x 256
    const unsigned short* __restrict__ Wh, const unsigned short* __restrict__ Wl,
    const float* __restrict__ Wf, const float* __restrict__ bias,
    const float* __restrict__ Pw, const float* __restrict__ Pb,
    const int* __restrict__ labels, float* __restrict__ out)
{
    __shared__ __align__(16) unsigned short X0h[8192], X0l[8192];     // 32 rows
    __shared__ __align__(16) unsigned short X1h[4096], X1l[4096];     // 16 rows
    __shared__ __align__(16) unsigned short BhT[2][8192], BlT[2][8192];
    __shared__ __align__(16) unsigned short Asth[2][1024], Astl[2][1024]; // 32 rows x 32k, 2 subtiles

    const int tid = threadIdx.x;
    const int w   = tid >> 6;      // 0..3
    const int l   = tid & 63;
    const int q   = l >> 4;
    const int rr  = l & 15;
    const int b   = blockIdx.x;

    auto stageB = [&](int buf, int k0) {
        if constexpr (WPREP) {
            #pragma unroll
            for (int j = 0; j < 8; ++j) {
                const int sb = w * 8 + j;          // 0..31
                const int s  = sb & 15;
                const size_t off = (size_t)(s * 16 + rr) * KDIM + k0 + q * 8;
                if (sb < 16) gload16(Wh + off, &BhT[buf][s * 512]);
                else         gload16(Wl + off, &BlT[buf][s * 512]);
            }
        } else {
            #pragma unroll
            for (int j = 0; j < 4; ++j) {
                const int u = w * 4 + j;           // 0..15
                const float* ws = Wf + (size_t)(u * 16 + rr) * KDIM + k0 + q * 8;
                float v[8];
                *(float4*)&v[0] = *(const float4*)ws;
                *(float4*)&v[4] = *(const float4*)(ws + 4);
                ushort8 hs, ls;
                #pragma unroll
                for (int i = 0; i < 8; ++i) {
                    const unsigned short h = f2h(v[i]);
                    hs[i] = h;
                    ls[i] = f2h(v[i] - h2f(h));
                }
                *(ushort8*)&BhT[buf][u * 512 + l * 8] = hs;
                *(ushort8*)&BlT[buf][u * 512 + l * 8] = ls;
            }
        }
    };

    // L5 A-stage: waves 0,1 own subtiles 0,1 (A rows w*16+rr of this block's 32)
    auto stageA = [&](int buf, int t) {
        if (w < 2) {
            const int k0   = t * 32;
            const int joff = k0 >> 8;
            const int c    = (k0 & 255) + q * 8;
            const size_t off = (size_t)(64 * b + 2 * (w * 16 + rr) + joff) * EMBED + c;
            gload16(A4h + off, &Asth[buf][w * 512]);
            gload16(A4l + off, &Astl[buf][w * 512]);
        }
    };

    float bv[4];
    #pragma unroll
    for (int ni = 0; ni < 4; ++ni) bv[ni] = bias[w * 64 + ni * 16 + rr];

    stageB(0, 0);
    stageA(0, 0);
    __syncthreads();

    int g = 0;
    for (int s = 0; s < 6; ++s) {
        unsigned short* srch = (s & 1) ? X0h : X1h;   // valid for s>=1
        unsigned short* srcl = (s & 1) ? X0l : X1l;
        unsigned short* dsth = (s & 1) ? X1h : X0h;
        unsigned short* dstl = (s & 1) ? X1l : X0l;
        const int Mout = 32 >> s;

        f32x4 acc[2][4] = {};
        for (int t = 0; t < 16; ++t, ++g) {
            const int cur = g & 1;
            if (g < 95) stageB(cur ^ 1, ((t + 1) & 15) * 32);
            if (s == 0 && t < 15) stageA(cur ^ 1, t + 1);

            const int k0   = t * 32;
            const int joff = k0 >> 8;
            const int c    = (k0 & 255) + q * 8;

            bf16x8 a_h0, a_l0;
            if (s == 0) {
                a_h0 = *(const bf16x8*)&Asth[cur][l * 8];
                a_l0 = *(const bf16x8*)&Astl[cur][l * 8];
            } else {
                const int row = 2 * rr + joff;
                const int idx = (row * 256 + c) ^ ((row & 7) << 3);
                a_h0 = *(const bf16x8*)&srch[idx];
                a_l0 = *(const bf16x8*)&srcl[idx];
            }

            bf16x8 bh4[4], bl4[4];
            #pragma unroll
            for (int ni = 0; ni < 4; ++ni) {
                bh4[ni] = *(const bf16x8*)&BhT[cur][(w * 4 + ni) * 512 + l * 8];
                bl4[ni] = *(const bf16x8*)&BlT[cur][(w * 4 + ni) * 512 + l * 8];
            }
            #pragma unroll
            for (int ni = 0; ni < 4; ++ni)
                acc[0][ni] = __builtin_amdgcn_mfma_f32_16x16x32_bf16(a_h0, bh4[ni], acc[0][ni], 0, 0, 0);
            #pragma unroll
            for (int ni = 0; ni < 4; ++ni)
                acc[0][ni] = __builtin_amdgcn_mfma_f32_16x16x32_bf16(a_l0, bh4[ni], acc[0][ni], 0, 0, 0);
            #pragma unroll
            for (int ni = 0; ni < 4; ++ni)
                acc[0][ni] = __builtin_amdgcn_mfma_f32_16x16x32_bf16(a_h0, bl4[ni], acc[0][ni], 0, 0, 0);

            if (s == 0) {   // second M-frag (rows 16..31) for L5
                const bf16x8 a_h1 = *(const bf16x8*)&Asth[cur][512 + l * 8];
                const bf16x8 a_l1 = *(const bf16x8*)&Astl[cur][512 + l * 8];
                #pragma unroll
                for (int ni = 0; ni < 4; ++ni)
                    acc[1][ni] = __builtin_amdgcn_mfma_f32_16x16x32_bf16(a_h1, bh4[ni], acc[1][ni], 0, 0, 0);
                #pragma unroll
                for (int ni = 0; ni < 4; ++ni)
                    acc[1][ni] = __builtin_amdgcn_mfma_f32_16x16x32_bf16(a_l1, bh4[ni], acc[1][ni], 0, 0, 0);
                #pragma unroll
                for (int ni = 0; ni < 4; ++ni)
                    acc[1][ni] = __builtin_amdgcn_mfma_f32_16x16x32_bf16(a_h1, bl4[ni], acc[1][ni], 0, 0, 0);
            }
            __syncthreads();
        }

        // epilogue -> X (swizzled); store valid rows only
        #pragma unroll
        for (int ni = 0; ni < 4; ++ni) {
            const int col = w * 64 + ni * 16 + rr;
            #pragma unroll
            for (int jj = 0; jj < 4; ++jj) {
                const int row = q * 4 + jj;
                if (row < Mout) {
                    const float y = fmaxf(acc[0][ni][jj] + bv[ni], 0.f);
                    const unsigned short h = f2h(y);
                    const int idx = (row * 256 + col) ^ ((row & 7) << 3);
                    dsth[idx] = h;
                    dstl[idx] = f2h(y - h2f(h));
                }
            }
            if (s == 0) {
                #pragma unroll
                for (int jj = 0; jj < 4; ++jj) {
                    const int row = 16 + q * 4 + jj;
                    const float y = fmaxf(acc[1][ni][jj] + bv[ni], 0.f);
                    const unsigned short h = f2h(y);
                    const int idx = (row * 256 + col) ^ ((row & 7) << 3);
                    dsth[idx] = h;
                    dstl[idx] = f2h(y - h2f(h));
                }
            }
        }
        __syncthreads();
    }

    // head: root = X1 row 0 (s=5 wrote X1; swizzle identity for row 0)
    if (w == 0) {
        float s0 = 0.f, s1 = 0.f;
        #pragma unroll
        for (int i = 0; i < 4; ++i) {
            const int col = l + i * 64;
            const float x = h2f(X1h[col]) + h2f(X1l[col]);
            s0 = fmaf(x, Pw[col], s0);
            s1 = fmaf(x, Pw[EMBED + col], s1);
        }
        #pragma unroll
        for (int off = 32; off > 0; off >>= 1) {
            s0 += __shfl_down(s0, off);
            s1 += __shfl_down(s1, off);
        }
        if (l == 0) {
            const float l0 = s0 + Pb[0];
            const float l1 = s1 + Pb[1];
            const int pred = (l1 > l0) ? 1 : 0;
            const float m  = fmaxf(l0, l1);
            const float lse = m + logf(expf(l0 - m) + expf(l1 - m));
            const int lab = labels[b];
            out[b]         = (float)pred;
            out[BATCH + b] = lse - (lab ? l1 : l0);
        }
    }
}

extern "C" void kernel_launch(void* const* d_in, const int* in_sizes, int n_in,
                              void* d_out, int out_size, void* d_ws, size_t ws_size,
                              hipStream_t stream)
{
    const int*   token_ids = (const int*)d_in[0];
    const int*   labels    = (const int*)d_in[1];
    const float* emb       = (const float*)d_in[2];
    const float* W_w       = (const float*)d_in[3];
    const float* W_b       = (const float*)d_in[4];
    const float* P_w       = (const float*)d_in[5];
    const float* P_b       = (const float*)d_in[6];
    float*       out       = (float*)d_out;

    // ws layout (ushort units):
    //   Ah/Al: odd-level outputs (L1, L3), 131072*256 each
    //   Bh/Bl: even-level outputs (L2, L4), 65536*256 each; ALSO hosts the
    //          pre-split emb tables Eh/El (12.8M <= 16.77M) during L1 —
    //          L2 overwrites them only after L1 completes.
    //   Wh/Wl: split weights
    unsigned short* Ah_buf = (unsigned short*)d_ws;
    unsigned short* Al_buf = Ah_buf + (size_t)131072 * 256;
    unsigned short* Bh_buf = Al_buf + (size_t)131072 * 256;
    unsigned short* Bl_buf = Bh_buf + (size_t)65536 * 256;
    unsigned short* Wh     = Bl_buf + (size_t)65536 * 256;
    unsigned short* Wl     = Wh + 131072;
    unsigned short* Eh     = Bh_buf;
    unsigned short* El     = Bl_buf;

    const size_t need_wprep = ((size_t)131072 * 256 * 2 + (size_t)65536 * 256 * 2 + 2 * 131072) * 2;
    const bool wprep = ws_size >= need_wprep;

    if (wprep) prep_w<<<512, 256, 0, stream>>>(W_w, Wh, Wl);
    prep_emb<<<(VOCAB * EMBED) / 2048, 256, 0, stream>>>(emb, Eh, El);

    if (wprep) {
        gemm_tree<1,1><<<1024, 512, 0, stream>>>(nullptr, nullptr, Wh, Wl, W_w, W_b, Ah_buf, Al_buf, token_ids, Eh, El);
        gemm_tree<0,1><<< 512, 512, 0, stream>>>(Ah_buf, Al_buf, Wh, Wl, W_w, W_b, Bh_buf, Bl_buf, nullptr, nullptr, nullptr);
        gemm_tree<0,1><<< 256, 512, 0, stream>>>(Bh_buf, Bl_buf, Wh, Wl, W_w, W_b, Ah_buf, Al_buf, nullptr, nullptr, nullptr);
        gemm_tree<0,1><<< 128, 512, 0, stream>>>(Ah_buf, Al_buf, Wh, Wl, W_w, W_b, Bh_buf, Bl_buf, nullptr, nullptr, nullptr);
        tail_kernel<1><<<BATCH, 256, 0, stream>>>(Bh_buf, Bl_buf, Wh, Wl, W_w, W_b, P_w, P_b, labels, out);
    } else {
        gemm_tree<1,0><<<1024, 512, 0, stream>>>(nullptr, nullptr, Wh, Wl, W_w, W_b, Ah_buf, Al_buf, token_ids, Eh, El);
        gemm_tree<0,0><<< 512, 512, 0, stream>>>(Ah_buf, Al_buf, Wh, Wl, W_w, W_b, Bh_buf, Bl_buf, nullptr, nullptr, nullptr);
        gemm_tree<0,0><<< 256, 512, 0, stream>>>(Bh_buf, Bl_buf, Wh, Wl, W_w, W_b, Ah_buf, Al_buf, nullptr, nullptr, nullptr);
        gemm_tree<0,0><<< 128, 512, 0, stream>>>(Ah_buf, Al_buf, Wh, Wl, W_w, W_b, Bh_buf, Bl_buf, nullptr, nullptr, nullptr);
        tail_kernel<0><<<BATCH, 256, 0, stream>>>(Bh_buf, Bl_buf, Wh, Wl, W_w, W_b, P_w, P_b, labels, out);
    }
}